// Round 28
// baseline (145.462 us; speedup 1.0000x reference)
//
#include <hip/hip_runtime.h>
#include <hip/hip_bf16.h>
#include <math.h>

#define B_ 4
#define S_ 2048
#define D_ 512
#define H_ 8
#define DK_ 64

typedef __bf16 bf16x8 __attribute__((ext_vector_type(8)));
typedef float f32x16 __attribute__((ext_vector_type(16)));
typedef float f32x4 __attribute__((ext_vector_type(4)));

static __device__ __forceinline__ unsigned short f2bf(float f) {
    unsigned int u = __builtin_bit_cast(unsigned int, f);
    unsigned int r = (u + 0x7FFFu + ((u >> 16) & 1u)) >> 16;
    return (unsigned short)r;
}

// ---- merged setup: W -> chunk-interleaved bf16 [d/8][n][8] (blocks 0..2047),
//      decay table (2048..2111) ----
__global__ __launch_bounds__(256) void k_setup(const float* __restrict__ wq, const float* __restrict__ wk,
                                               unsigned short* __restrict__ wqT2, unsigned short* __restrict__ wkT2,
                                               float* __restrict__ tab) {
    const int bx = blockIdx.x;
    if (bx < 2048) {
        int idx = bx * 256 + threadIdx.x;
        const int n = H_ * DK_ * D_;
        const float* src = idx < n ? wq : wk;
        unsigned short* dst = idx < n ? wqT2 : wkT2;
        int o = idx < n ? idx : idx - n;
        int d  = o % D_;
        int hk = o / D_;          // h*64 + k
        int h  = hk / DK_;
        int k  = hk % DK_;
        dst[(((size_t)(d >> 3) * 512 + hk) << 3) + (d & 7)] = f2bf(src[(h * D_ + d) * DK_ + k]);
    } else {
        int i = (bx - 2048) * 256 + threadIdx.x;
        if (i < H_ * S_) {
            int h = i / S_;
            int n = i % S_;
            double xv = -3.4657359027997265 - (double)h * (2.772588722239781 / 7.0);
            double g = 1.0 - exp(xv);
            tab[i] = (float)pow(g, (double)n);
        }
    }
}

// ---- one fill unit: i<7 -> one upper-zero 64x256 supertile; i==7 -> out0 chunk ----
static __device__ __forceinline__ void fill_step(int bid, int i, int tid,
        float* __restrict__ aout, float* __restrict__ out0) {
    f32x4 z = {0.f, 0.f, 0.f, 0.f};
    if (i < 7) {
        const int f = bid * 7 + i;
        const int bh = f / 112;
        int r = f % 112;
        int g = 0, cum = 0;
        for (; g < 7; ++g) { int cnt = 4 * (7 - g); if (r < cum + cnt) break; cum += cnt; }
        const int rr  = r - cum;
        const int per = 7 - g;
        const int panel = g * 4 + rr / per;
        const int st    = g + 1 + rr % per;
        float* base = aout + (size_t)bh * S_ * S_ + (size_t)(panel * 64) * S_ + st * 256;
#pragma unroll
        for (int j = 0; j < 16; ++j) {
            int u = tid + j * 256;
            *reinterpret_cast<f32x4*>(base + (size_t)(u >> 6) * S_ + (u & 63) * 4) = z;
        }
    } else {
        f32x4* b0 = reinterpret_cast<f32x4*>(out0) + (size_t)bid * 2048;
#pragma unroll
        for (int j = 0; j < 8; ++j)
            b0[tid + j * 256] = z;
    }
}

// ---- projection GEMM v7: v5 + chunk-level register ping-pong B prefetch ----
// Chunk ch's 16 B-frags load during chunk ch-1's MFMAs + fill stores, hiding
// the ~300cyc L2 latency that made v5 latency-bound (MfmaUtil 4.5%). Two
// NAMED register sets (bA/bB) keep all indexing compile-time (no scratch).
__global__ __launch_bounds__(256, 2) void k_proj(const float* __restrict__ x,
                                                 const unsigned short* __restrict__ wqT2,
                                                 const unsigned short* __restrict__ wkT2,
                                                 unsigned short* __restrict__ qb,
                                                 unsigned short* __restrict__ kb,
                                                 float* __restrict__ aout,
                                                 float* __restrict__ out0) {
    const int tid  = threadIdx.x;
    const int lane = tid & 63;
    const int wave = tid >> 6;
    const int m0   = blockIdx.x * 32;
    const int bidx = m0 >> 11;
    const int s0   = m0 & 2047;
    const int half = blockIdx.y;
    const int fid  = blockIdx.y * 256 + blockIdx.x;   // flat 0..511 for fill
    const unsigned short* wt = half ? wkT2 : wqT2;
    unsigned short* outp     = half ? kb  : qb;

    __shared__ unsigned short atile[32 * 520];   // A: 32 rows x 512 d
    __shared__ unsigned short otile[32 * 520];   // out: 32 s x 512 n

    // stage A f32 -> bf16 (coalesced 1KB/instr)
    {
        const float4* xsrc = reinterpret_cast<const float4*>(x + (size_t)m0 * D_);
#pragma unroll
        for (int i = 0; i < 16; ++i) {
            int u   = tid + i * 256;
            int row = u >> 7, c4 = u & 127;
            float4 v = xsrc[u];
            ushort4 o;
            o.x = f2bf(v.x); o.y = f2bf(v.y); o.z = f2bf(v.z); o.w = f2bf(v.w);
            *reinterpret_cast<ushort4*>(&atile[row * 520 + c4 * 4]) = o;
        }
    }
    __syncthreads();

    const int col = lane & 31;      // A row / B col / C col
    const int hi  = lane >> 5;      // k-group
    const int n0  = wave * 128;
    const unsigned short* ap = atile + col * 520 + hi * 8;

    f32x16 acc0 = {}, acc1 = {}, acc2 = {}, acc3 = {};
    const unsigned short* bp0 = wt + hi * 4096 + (size_t)(n0 + col) * 8;

#define LOADB(DST, CH) { \
    const unsigned short* bb_ = bp0 + (size_t)(CH) * 4 * 8192; \
    _Pragma("unroll") \
    for (int k4 = 0; k4 < 4; ++k4) { \
        DST[k4][0] = *reinterpret_cast<const bf16x8*>(bb_ + k4 * 8192); \
        DST[k4][1] = *reinterpret_cast<const bf16x8*>(bb_ + k4 * 8192 + 256); \
        DST[k4][2] = *reinterpret_cast<const bf16x8*>(bb_ + k4 * 8192 + 512); \
        DST[k4][3] = *reinterpret_cast<const bf16x8*>(bb_ + k4 * 8192 + 768); \
    } }

#define COMP(BREG, CH) { \
    _Pragma("unroll") \
    for (int k4 = 0; k4 < 4; ++k4) { \
        bf16x8 a_ = *reinterpret_cast<const bf16x8*>(ap + ((CH) * 4 + k4) * 16); \
        acc0 = __builtin_amdgcn_mfma_f32_32x32x16_bf16(a_, BREG[k4][0], acc0, 0, 0, 0); \
        acc1 = __builtin_amdgcn_mfma_f32_32x32x16_bf16(a_, BREG[k4][1], acc1, 0, 0, 0); \
        acc2 = __builtin_amdgcn_mfma_f32_32x32x16_bf16(a_, BREG[k4][2], acc2, 0, 0, 0); \
        acc3 = __builtin_amdgcn_mfma_f32_32x32x16_bf16(a_, BREG[k4][3], acc3, 0, 0, 0); \
    } }

    bf16x8 bA[4][4], bB[4][4];
    LOADB(bA, 0);
#pragma unroll 1
    for (int cc2 = 0; cc2 < 4; ++cc2) {
        const int ch0 = cc2 * 2, ch1 = ch0 + 1;
        fill_step(fid, ch0, tid, aout, out0);
        LOADB(bB, ch1);                      // prefetch odd chunk
        COMP(bA, ch0);                       // compute even chunk (loads long done)
        fill_step(fid, ch1, tid, aout, out0);
        if (cc2 < 3) LOADB(bA, ch1 + 1);     // prefetch next even chunk
        COMP(bB, ch1);                       // compute odd chunk
    }
#undef LOADB
#undef COMP

    // epilogue -> otile (C layout: col = lane&31, rows rowD)
#define EPO(ACC, NB) { \
    int n = n0 + (NB) * 32 + col; \
    _Pragma("unroll") \
    for (int r = 0; r < 16; ++r) { \
        int rowD = (r & 3) + 8 * (r >> 2) + 4 * hi; \
        otile[rowD * 520 + n] = f2bf(ACC[r]); \
    } }
    EPO(acc0, 0) EPO(acc1, 1) EPO(acc2, 2) EPO(acc3, 3)
#undef EPO
    __syncthreads();

    // store: per head, 32 s-rows x 64 k = 4KB contiguous; 16B/lane linear
#pragma unroll
    for (int i = 0; i < 8; ++i) {
        int u    = tid + i * 256;
        int head = u >> 8;
        int v    = u & 255;
        int s    = v >> 3;
        int kc   = v & 7;
        f32x4 val = *reinterpret_cast<const f32x4*>(&otile[s * 520 + head * 64 + kc * 8]);
        unsigned short* dst = outp + (((size_t)(bidx * H_ + head) * S_ + s0 + s) * DK_) + kc * 8;
        *reinterpret_cast<f32x4*>(dst) = val;
    }
}

// ---- pure score (identical to R25/R27) ----
__global__ __launch_bounds__(256) void k_score(const unsigned short* __restrict__ qb,
                                               const unsigned short* __restrict__ kb,
                                               const float* __restrict__ tab,
                                               float* __restrict__ aout) {
    __shared__ __align__(16) float tile[64 * 256];
    const int id  = blockIdx.x;
    const int tid = threadIdx.x;
    const int lane = tid & 63;
    const int w    = tid >> 6;
    const int c    = id & 7, sidx = id >> 3;
    const int bh   = (c >> 1) + 4 * (sidx >> 3);
    const int p    = ((sidx & 7) << 1) | (c & 1);
    const int h    = bh & (H_ - 1);
    float* ablk = aout + (size_t)bh * S_ * S_;
    const float* th = tab + h * S_;

    const int col  = lane & 31;
    const int hi   = lane >> 5;
    const int koff = hi * 8;

    const float c1 = 1.0f / th[col];
    float grc[16];
    int rowDv[16];
#pragma unroll
    for (int r = 0; r < 16; ++r) {
        rowDv[r] = (r & 3) + 8 * (r >> 2) + 4 * hi;
        grc[r] = th[rowDv[r]] * c1;
    }

    for (int pp = 0; pp < 2; ++pp) {
        const int panel = pp ? (31 - p) : p;
        const int s0 = panel * 64;
        const int qq = panel >> 2;
        const int rb = panel & 3;

        bf16x8 qf[2][4];
#pragma unroll
        for (int rg = 0; rg < 2; ++rg) {
            const unsigned short* qp = qb + ((size_t)bh * S_ + s0 + rg * 32 + col) * DK_ + koff;
#pragma unroll
            for (int i = 0; i < 4; ++i)
                qf[rg][i] = *reinterpret_cast<const bf16x8*>(qp + 16 * i);
        }

        for (int st = 0; st <= qq; ++st) {
            const int t0 = st * 256;
            const int ct0 = t0 + w * 64;
            const bool active = (st < qq) || (w <= rb);
            if (active) {
                f32x16 acc[2][2] = {{{}, {}}, {{}, {}}};
#pragma unroll
                for (int cg = 0; cg < 2; ++cg) {
                    const unsigned short* kp = kb + ((size_t)bh * S_ + ct0 + cg * 32 + col) * DK_ + koff;
                    bf16x8 kf0 = *reinterpret_cast<const bf16x8*>(kp);
                    bf16x8 kf1 = *reinterpret_cast<const bf16x8*>(kp + 16);
                    bf16x8 kf2 = *reinterpret_cast<const bf16x8*>(kp + 32);
                    bf16x8 kf3 = *reinterpret_cast<const bf16x8*>(kp + 48);
#pragma unroll
                    for (int rg = 0; rg < 2; ++rg) {
                        acc[rg][cg] = __builtin_amdgcn_mfma_f32_32x32x16_bf16(qf[rg][0], kf0, acc[rg][cg], 0, 0, 0);
                        acc[rg][cg] = __builtin_amdgcn_mfma_f32_32x32x16_bf16(qf[rg][1], kf1, acc[rg][cg], 0, 0, 0);
                        acc[rg][cg] = __builtin_amdgcn_mfma_f32_32x32x16_bf16(qf[rg][2], kf2, acc[rg][cg], 0, 0, 0);
                        acc[rg][cg] = __builtin_amdgcn_mfma_f32_32x32x16_bf16(qf[rg][3], kf3, acc[rg][cg], 0, 0, 0);
                    }
                }
                if (st < qq || w < rb) {
#pragma unroll
                    for (int rg = 0; rg < 2; ++rg) {
#pragma unroll
                        for (int cg = 0; cg < 2; ++cg) {
                            const float sc = th[s0 + rg * 32 - ct0 - cg * 32];
#pragma unroll
                            for (int r = 0; r < 16; ++r)
                                tile[(rg * 32 + rowDv[r]) * 256 + w * 64 + cg * 32 + col] =
                                    acc[rg][cg][r] * grc[r] * sc;
                        }
                    }
                } else {
#pragma unroll
                    for (int rg = 0; rg < 2; ++rg) {
#pragma unroll
                        for (int cg = 0; cg < 2; ++cg) {
                            const int dbase = 32 * (rg - cg);
#pragma unroll
                            for (int r = 0; r < 16; ++r) {
                                int d = dbase + rowDv[r] - col;
                                float v = (d >= 0) ? acc[rg][cg][r] * th[d] : 0.0f;
                                tile[(rg * 32 + rowDv[r]) * 256 + w * 64 + cg * 32 + col] = v;
                            }
                        }
                    }
                }
            } else {
                f32x4 z = {0.f, 0.f, 0.f, 0.f};
#pragma unroll
                for (int i = 0; i < 16; ++i) {
                    int r = i * 4 + (lane >> 4);
                    int cc = (lane & 15) * 4;
                    *reinterpret_cast<f32x4*>(&tile[r * 256 + w * 64 + cc]) = z;
                }
            }
            __syncthreads();
#pragma unroll
            for (int r = 0; r < 16; ++r) {
                int row = w * 16 + r;
                f32x4 v = *reinterpret_cast<const f32x4*>(&tile[row * 256 + lane * 4]);
                *reinterpret_cast<f32x4*>(ablk + (size_t)(s0 + row) * S_ + t0 + lane * 4) = v;
            }
            __syncthreads();
        }
    }
}

extern "C" void kernel_launch(void* const* d_in, const int* in_sizes, int n_in,
                              void* d_out, int out_size, void* d_ws, size_t ws_size,
                              hipStream_t stream) {
    const float* x  = (const float*)d_in[0];
    const float* wq = (const float*)d_in[1];
    const float* wk = (const float*)d_in[2];

    char* ws = (char*)d_ws;
    unsigned short* wqT2 = (unsigned short*)(ws);              //    524,288 B
    unsigned short* wkT2 = (unsigned short*)(ws + 524288);     //    524,288 B
    unsigned short* qb   = (unsigned short*)(ws + 1048576);    //  8,388,608 B
    unsigned short* kb   = (unsigned short*)(ws + 9437184);    //  8,388,608 B
    float*          tab  = (float*)(ws + 17825792);            //     65,536 B

    float* out0 = (float*)d_out;
    float* aout = (float*)d_out + (size_t)B_ * S_ * D_;

    hipLaunchKernelGGL(k_setup, dim3(2112), dim3(256), 0, stream,
                       wq, wk, wqT2, wkT2, tab);
    hipLaunchKernelGGL(k_proj, dim3(B_*S_/32, 2), dim3(256), 0, stream,
                       x, wqT2, wkT2, qb, kb, aout, out0);
    hipLaunchKernelGGL(k_score, dim3(512), dim3(256), 0, stream,
                       qb, kb, tab, aout);
}

// Round 29
// 142.692 us; speedup vs baseline: 1.0194x; 1.0194x over previous
//
#include <hip/hip_runtime.h>
#include <hip/hip_bf16.h>
#include <math.h>

#define B_ 4
#define S_ 2048
#define D_ 512
#define H_ 8
#define DK_ 64

typedef __bf16 bf16x8 __attribute__((ext_vector_type(8)));
typedef float f32x16 __attribute__((ext_vector_type(16)));
typedef float f32x4 __attribute__((ext_vector_type(4)));

static __device__ __forceinline__ unsigned short f2bf(float f) {
    unsigned int u = __builtin_bit_cast(unsigned int, f);
    unsigned int r = (u + 0x7FFFu + ((u >> 16) & 1u)) >> 16;
    return (unsigned short)r;
}

// ---- merged setup: W -> chunk-interleaved bf16 [d/8][n][8] (blocks 0..2047),
//      decay table (2048..2111) ----
__global__ __launch_bounds__(256) void k_setup(const float* __restrict__ wq, const float* __restrict__ wk,
                                               unsigned short* __restrict__ wqT2, unsigned short* __restrict__ wkT2,
                                               float* __restrict__ tab) {
    const int bx = blockIdx.x;
    if (bx < 2048) {
        int idx = bx * 256 + threadIdx.x;
        const int n = H_ * DK_ * D_;
        const float* src = idx < n ? wq : wk;
        unsigned short* dst = idx < n ? wqT2 : wkT2;
        int o = idx < n ? idx : idx - n;
        int d  = o % D_;
        int hk = o / D_;          // h*64 + k
        int h  = hk / DK_;
        int k  = hk % DK_;
        dst[(((size_t)(d >> 3) * 512 + hk) << 3) + (d & 7)] = f2bf(src[(h * D_ + d) * DK_ + k]);
    } else {
        int i = (bx - 2048) * 256 + threadIdx.x;
        if (i < H_ * S_) {
            int h = i / S_;
            int n = i % S_;
            double xv = -3.4657359027997265 - (double)h * (2.772588722239781 / 7.0);
            double g = 1.0 - exp(xv);
            tab[i] = (float)pow(g, (double)n);
        }
    }
}

// ---- one fill unit: i<7 -> one upper-zero 64x256 supertile; i==7 -> out0 chunk ----
static __device__ __forceinline__ void fill_step(int bid, int i, int tid,
        float* __restrict__ aout, float* __restrict__ out0) {
    f32x4 z = {0.f, 0.f, 0.f, 0.f};
    if (i < 7) {
        const int f = bid * 7 + i;
        const int bh = f / 112;
        int r = f % 112;
        int g = 0, cum = 0;
        for (; g < 7; ++g) { int cnt = 4 * (7 - g); if (r < cum + cnt) break; cum += cnt; }
        const int rr  = r - cum;
        const int per = 7 - g;
        const int panel = g * 4 + rr / per;
        const int st    = g + 1 + rr % per;
        float* base = aout + (size_t)bh * S_ * S_ + (size_t)(panel * 64) * S_ + st * 256;
#pragma unroll
        for (int j = 0; j < 16; ++j) {
            int u = tid + j * 256;
            *reinterpret_cast<f32x4*>(base + (size_t)(u >> 6) * S_ + (u & 63) * 4) = z;
        }
    } else {
        f32x4* b0 = reinterpret_cast<f32x4*>(out0) + (size_t)bid * 2048;
#pragma unroll
        for (int j = 0; j < 8; ++j)
            b0[tid + j * 256] = z;
    }
}

// ---- projection GEMM v5 (R25/R27 exact — best known): coalesced B +
//      LDS-staged linear stores + interleaved fill; 2 blocks/CU ----
__global__ __launch_bounds__(256, 2) void k_proj(const float* __restrict__ x,
                                                 const unsigned short* __restrict__ wqT2,
                                                 const unsigned short* __restrict__ wkT2,
                                                 unsigned short* __restrict__ qb,
                                                 unsigned short* __restrict__ kb,
                                                 float* __restrict__ aout,
                                                 float* __restrict__ out0) {
    const int tid  = threadIdx.x;
    const int lane = tid & 63;
    const int wave = tid >> 6;
    const int m0   = blockIdx.x * 32;
    const int bidx = m0 >> 11;
    const int s0   = m0 & 2047;
    const int half = blockIdx.y;
    const int fid  = blockIdx.y * 256 + blockIdx.x;   // flat 0..511 for fill
    const unsigned short* wt = half ? wkT2 : wqT2;
    unsigned short* outp     = half ? kb  : qb;

    __shared__ unsigned short atile[32 * 520];   // A: 32 rows x 512 d
    __shared__ unsigned short otile[32 * 520];   // out: 32 s x 512 n

    // stage A f32 -> bf16 (coalesced 1KB/instr)
    {
        const float4* xsrc = reinterpret_cast<const float4*>(x + (size_t)m0 * D_);
#pragma unroll
        for (int i = 0; i < 16; ++i) {
            int u   = tid + i * 256;
            int row = u >> 7, c4 = u & 127;
            float4 v = xsrc[u];
            ushort4 o;
            o.x = f2bf(v.x); o.y = f2bf(v.y); o.z = f2bf(v.z); o.w = f2bf(v.w);
            *reinterpret_cast<ushort4*>(&atile[row * 520 + c4 * 4]) = o;
        }
    }
    __syncthreads();

    const int col = lane & 31;      // A row / B col / C col
    const int hi  = lane >> 5;      // k-group
    const int n0  = wave * 128;
    const unsigned short* ap = atile + col * 520 + hi * 8;

    f32x16 acc0 = {}, acc1 = {}, acc2 = {}, acc3 = {};
    const unsigned short* bp0 = wt + hi * 4096 + (size_t)(n0 + col) * 8;
    // 8 chunks x 4 ks; one fill unit per chunk (stores drain under B-load latency)
#pragma unroll 1
    for (int ch = 0; ch < 8; ++ch) {
        fill_step(fid, ch, tid, aout, out0);
#pragma unroll
        for (int k4 = 0; k4 < 4; ++k4) {
            const int ks = ch * 4 + k4;
            bf16x8 a = *reinterpret_cast<const bf16x8*>(ap + ks * 16);
            const unsigned short* bp = bp0 + ks * 8192;
            acc0 = __builtin_amdgcn_mfma_f32_32x32x16_bf16(a, *reinterpret_cast<const bf16x8*>(bp),        acc0, 0, 0, 0);
            acc1 = __builtin_amdgcn_mfma_f32_32x32x16_bf16(a, *reinterpret_cast<const bf16x8*>(bp + 256),  acc1, 0, 0, 0);
            acc2 = __builtin_amdgcn_mfma_f32_32x32x16_bf16(a, *reinterpret_cast<const bf16x8*>(bp + 512),  acc2, 0, 0, 0);
            acc3 = __builtin_amdgcn_mfma_f32_32x32x16_bf16(a, *reinterpret_cast<const bf16x8*>(bp + 768),  acc3, 0, 0, 0);
        }
    }

    // epilogue -> otile (C layout: col = lane&31, rows rowD)
#define EPO(ACC, NB) { \
    int n = n0 + (NB) * 32 + col; \
    _Pragma("unroll") \
    for (int r = 0; r < 16; ++r) { \
        int rowD = (r & 3) + 8 * (r >> 2) + 4 * hi; \
        otile[rowD * 520 + n] = f2bf(ACC[r]); \
    } }
    EPO(acc0, 0) EPO(acc1, 1) EPO(acc2, 2) EPO(acc3, 3)
#undef EPO
    __syncthreads();

    // store: per head, 32 s-rows x 64 k = 4KB contiguous; 16B/lane linear
#pragma unroll
    for (int i = 0; i < 8; ++i) {
        int u    = tid + i * 256;
        int head = u >> 8;
        int v    = u & 255;
        int s    = v >> 3;
        int kc   = v & 7;
        f32x4 val = *reinterpret_cast<const f32x4*>(&otile[s * 520 + head * 64 + kc * 8]);
        unsigned short* dst = outp + (((size_t)(bidx * H_ + head) * S_ + s0 + s) * DK_) + kc * 8;
        *reinterpret_cast<f32x4*>(dst) = val;
    }
}

// ---- pure score (identical to R25/R27) ----
__global__ __launch_bounds__(256) void k_score(const unsigned short* __restrict__ qb,
                                               const unsigned short* __restrict__ kb,
                                               const float* __restrict__ tab,
                                               float* __restrict__ aout) {
    __shared__ __align__(16) float tile[64 * 256];
    const int id  = blockIdx.x;
    const int tid = threadIdx.x;
    const int lane = tid & 63;
    const int w    = tid >> 6;
    const int c    = id & 7, sidx = id >> 3;
    const int bh   = (c >> 1) + 4 * (sidx >> 3);
    const int p    = ((sidx & 7) << 1) | (c & 1);
    const int h    = bh & (H_ - 1);
    float* ablk = aout + (size_t)bh * S_ * S_;
    const float* th = tab + h * S_;

    const int col  = lane & 31;
    const int hi   = lane >> 5;
    const int koff = hi * 8;

    const float c1 = 1.0f / th[col];
    float grc[16];
    int rowDv[16];
#pragma unroll
    for (int r = 0; r < 16; ++r) {
        rowDv[r] = (r & 3) + 8 * (r >> 2) + 4 * hi;
        grc[r] = th[rowDv[r]] * c1;
    }

    for (int pp = 0; pp < 2; ++pp) {
        const int panel = pp ? (31 - p) : p;
        const int s0 = panel * 64;
        const int qq = panel >> 2;
        const int rb = panel & 3;

        bf16x8 qf[2][4];
#pragma unroll
        for (int rg = 0; rg < 2; ++rg) {
            const unsigned short* qp = qb + ((size_t)bh * S_ + s0 + rg * 32 + col) * DK_ + koff;
#pragma unroll
            for (int i = 0; i < 4; ++i)
                qf[rg][i] = *reinterpret_cast<const bf16x8*>(qp + 16 * i);
        }

        for (int st = 0; st <= qq; ++st) {
            const int t0 = st * 256;
            const int ct0 = t0 + w * 64;
            const bool active = (st < qq) || (w <= rb);
            if (active) {
                f32x16 acc[2][2] = {{{}, {}}, {{}, {}}};
#pragma unroll
                for (int cg = 0; cg < 2; ++cg) {
                    const unsigned short* kp = kb + ((size_t)bh * S_ + ct0 + cg * 32 + col) * DK_ + koff;
                    bf16x8 kf0 = *reinterpret_cast<const bf16x8*>(kp);
                    bf16x8 kf1 = *reinterpret_cast<const bf16x8*>(kp + 16);
                    bf16x8 kf2 = *reinterpret_cast<const bf16x8*>(kp + 32);
                    bf16x8 kf3 = *reinterpret_cast<const bf16x8*>(kp + 48);
#pragma unroll
                    for (int rg = 0; rg < 2; ++rg) {
                        acc[rg][cg] = __builtin_amdgcn_mfma_f32_32x32x16_bf16(qf[rg][0], kf0, acc[rg][cg], 0, 0, 0);
                        acc[rg][cg] = __builtin_amdgcn_mfma_f32_32x32x16_bf16(qf[rg][1], kf1, acc[rg][cg], 0, 0, 0);
                        acc[rg][cg] = __builtin_amdgcn_mfma_f32_32x32x16_bf16(qf[rg][2], kf2, acc[rg][cg], 0, 0, 0);
                        acc[rg][cg] = __builtin_amdgcn_mfma_f32_32x32x16_bf16(qf[rg][3], kf3, acc[rg][cg], 0, 0, 0);
                    }
                }
                if (st < qq || w < rb) {
#pragma unroll
                    for (int rg = 0; rg < 2; ++rg) {
#pragma unroll
                        for (int cg = 0; cg < 2; ++cg) {
                            const float sc = th[s0 + rg * 32 - ct0 - cg * 32];
#pragma unroll
                            for (int r = 0; r < 16; ++r)
                                tile[(rg * 32 + rowDv[r]) * 256 + w * 64 + cg * 32 + col] =
                                    acc[rg][cg][r] * grc[r] * sc;
                        }
                    }
                } else {
#pragma unroll
                    for (int rg = 0; rg < 2; ++rg) {
#pragma unroll
                        for (int cg = 0; cg < 2; ++cg) {
                            const int dbase = 32 * (rg - cg);
#pragma unroll
                            for (int r = 0; r < 16; ++r) {
                                int d = dbase + rowDv[r] - col;
                                float v = (d >= 0) ? acc[rg][cg][r] * th[d] : 0.0f;
                                tile[(rg * 32 + rowDv[r]) * 256 + w * 64 + cg * 32 + col] = v;
                            }
                        }
                    }
                }
            } else {
                f32x4 z = {0.f, 0.f, 0.f, 0.f};
#pragma unroll
                for (int i = 0; i < 16; ++i) {
                    int r = i * 4 + (lane >> 4);
                    int cc = (lane & 15) * 4;
                    *reinterpret_cast<f32x4*>(&tile[r * 256 + w * 64 + cc]) = z;
                }
            }
            __syncthreads();
#pragma unroll
            for (int r = 0; r < 16; ++r) {
                int row = w * 16 + r;
                f32x4 v = *reinterpret_cast<const f32x4*>(&tile[row * 256 + lane * 4]);
                *reinterpret_cast<f32x4*>(ablk + (size_t)(s0 + row) * S_ + t0 + lane * 4) = v;
            }
            __syncthreads();
        }
    }
}

extern "C" void kernel_launch(void* const* d_in, const int* in_sizes, int n_in,
                              void* d_out, int out_size, void* d_ws, size_t ws_size,
                              hipStream_t stream) {
    const float* x  = (const float*)d_in[0];
    const float* wq = (const float*)d_in[1];
    const float* wk = (const float*)d_in[2];

    char* ws = (char*)d_ws;
    unsigned short* wqT2 = (unsigned short*)(ws);              //    524,288 B
    unsigned short* wkT2 = (unsigned short*)(ws + 524288);     //    524,288 B
    unsigned short* qb   = (unsigned short*)(ws + 1048576);    //  8,388,608 B
    unsigned short* kb   = (unsigned short*)(ws + 9437184);    //  8,388,608 B
    float*          tab  = (float*)(ws + 17825792);            //     65,536 B

    float* out0 = (float*)d_out;
    float* aout = (float*)d_out + (size_t)B_ * S_ * D_;

    hipLaunchKernelGGL(k_setup, dim3(2112), dim3(256), 0, stream,
                       wq, wk, wqT2, wkT2, tab);
    hipLaunchKernelGGL(k_proj, dim3(B_*S_/32, 2), dim3(256), 0, stream,
                       x, wqT2, wkT2, qb, kb, aout, out0);
    hipLaunchKernelGGL(k_score, dim3(512), dim3(256), 0, stream,
                       qb, kb, tab, aout);
}